// Round 24
// baseline (253.523 us; speedup 1.0000x reference)
//
#include <hip/hip_runtime.h>
#include <hip/hip_bf16.h>
#include <hip/hip_fp16.h>

#define D 128

__device__ __forceinline__ float bf2f(unsigned short u) {
  return __uint_as_float(((unsigned int)u) << 16);
}
__device__ __forceinline__ unsigned short f2bf(float f) {
  unsigned int x = __float_as_uint(f);
  x += 0x7fff + ((x >> 16) & 1);
  return (unsigned short)(x >> 16);
}
__device__ __forceinline__ float h2f(unsigned short b) {
  return __half2float(__ushort_as_half(b));
}

// flags: [0..4]=float tensor is-bf16 (emb,W1,b1,W2,b2), [5]=ints-int64

__global__ void k_detect_f5(const unsigned short* __restrict__ t0, int n0,
                            const unsigned short* __restrict__ t1, int n1,
                            const unsigned short* __restrict__ t2, int n2,
                            const unsigned short* __restrict__ t3, int n3,
                            const unsigned short* __restrict__ t4, int n4,
                            int* __restrict__ flag) {
  const unsigned short* tabs[5] = {t0, t1, t2, t3, t4};
  int ns[5] = {n0, n1, n2, n3, n4};
  int b = blockIdx.x;
  const unsigned short* u16 = tabs[b];
  int n = ns[b];
  __shared__ int cnt;
  int K = n / 2 < 256 ? n / 2 : 256;
  if (threadIdx.x == 0) cnt = 0;
  __syncthreads();
  if (threadIdx.x < K) {
    unsigned short u = u16[threadIdx.x * 2];
    int e = (u >> 7) & 0xFF;
    if (u == 0 || (e >= 100 && e <= 140)) atomicAdd(&cnt, 1);
  }
  __syncthreads();
  if (threadIdx.x == 0) flag[b] = (cnt * 2 >= K) ? 1 : 0;
}

__global__ void k_detect_i(const unsigned int* __restrict__ ei32,
                           int* __restrict__ flagSlot) {
  __shared__ int z;
  if (threadIdx.x == 0) z = 0;
  __syncthreads();
  if (ei32[threadIdx.x * 2 + 1] == 0u) atomicAdd(&z, 1);
  __syncthreads();
  if (threadIdx.x == 0) *flagSlot = (z >= 60) ? 1 : 0;
}

__global__ void k_conv(const void* __restrict__ src, float* __restrict__ dst,
                       int n, const int* __restrict__ flagSlot) {
  int i = blockIdx.x * blockDim.x + threadIdx.x;
  if (i >= n) return;
  if (*flagSlot) dst[i] = bf2f(((const unsigned short*)src)[i]);
  else           dst[i] = ((const float*)src)[i];
}

__global__ void k_conv_params(const void* __restrict__ W1, const void* __restrict__ b1,
                              const void* __restrict__ W2, const void* __restrict__ b2,
                              float* __restrict__ W1f, float* __restrict__ b1f,
                              float* __restrict__ W2f, float* __restrict__ b2f,
                              const int* __restrict__ flag) {
  int i = blockIdx.x * blockDim.x + threadIdx.x;
  const int S = D * D;
  const void* src; float* dst; int j; const int* fs;
  if (i < S)                { src = W1; dst = W1f; j = i;            fs = flag + 1; }
  else if (i < S + D)       { src = b1; dst = b1f; j = i - S;        fs = flag + 2; }
  else if (i < 2 * S + D)   { src = W2; dst = W2f; j = i - S - D;    fs = flag + 3; }
  else if (i < 2 * S + 2*D) { src = b2; dst = b2f; j = i - 2*S - D;  fs = flag + 4; }
  else return;
  if (*fs) dst[j] = bf2f(((const unsigned short*)src)[j]);
  else     dst[j] = ((const float*)src)[j];
}

// int conversion for x/batch + in-degree count straight off raw edge tensor
__global__ void k_convi_all(const void* __restrict__ xr, const void* __restrict__ eir,
                            const void* __restrict__ br,
                            int* __restrict__ xs, int* __restrict__ batchs,
                            int* __restrict__ indeg,
                            int nn, int ne, int vocab, int ng,
                            const int* __restrict__ flag64) {
  long long i = (long long)blockIdx.x * blockDim.x + threadIdx.x;
  int is64 = *flag64;
  if (i < nn) {
    int v = is64 ? (int)((const long long*)xr)[i] : ((const int*)xr)[i];
    v = v < 0 ? 0 : (v > vocab - 1 ? vocab - 1 : v);
    xs[i] = v;
  } else if (i < (long long)nn + ne) {
    long long j = i - nn;
    int v = is64 ? (int)((const long long*)eir)[ne + j] : ((const int*)eir)[ne + j];
    v = v < 0 ? 0 : (v > nn - 1 ? nn - 1 : v);
    atomicAdd(&indeg[v], 1);
  } else if (i < (long long)nn + ne + nn) {
    long long j = i - nn - ne;
    int v = is64 ? (int)((const long long*)br)[j] : ((const int*)br)[j];
    v = v < 0 ? 0 : (v > ng - 1 ? ng - 1 : v);
    batchs[j] = v;
  }
}

// ---------------- CSR scan -------------------------------------------------
__global__ __launch_bounds__(1024) void k_scan1(const int* __restrict__ indeg,
                                                int* __restrict__ off,
                                                int* __restrict__ bsum, int nn) {
  int t = threadIdx.x;
  int idx = blockIdx.x * 1024 + t;
  int v = (idx < nn) ? indeg[idx] : 0;
  int lane = t & 63, wid = t >> 6;
  int inc = v;
  #pragma unroll
  for (int d = 1; d < 64; d <<= 1) {
    int u = __shfl_up(inc, d);
    if (lane >= d) inc += u;
  }
  __shared__ int ws[16];
  if (lane == 63) ws[wid] = inc;
  __syncthreads();
  if (wid == 0) {
    int wv = (lane < 16) ? ws[lane] : 0;
    #pragma unroll
    for (int d = 1; d < 16; d <<= 1) {
      int u = __shfl_up(wv, d);
      if (lane >= d) wv += u;
    }
    if (lane < 16) ws[lane] = wv;
  }
  __syncthreads();
  int base = wid ? ws[wid - 1] : 0;
  if (idx < nn) off[idx] = base + inc - v;
  if (t == 1023) bsum[blockIdx.x] = ws[15];
}

__global__ void k_scan2(int* __restrict__ bsum, int nb) {
  if (blockIdx.x == 0 && threadIdx.x == 0) {
    int run = 0;
    for (int i = 0; i < nb; ++i) { int s = bsum[i]; bsum[i] = run; run += s; }
  }
}

__global__ void k_scan3(int* __restrict__ off, int* __restrict__ cursor,
                        float* __restrict__ dis, const int* __restrict__ indeg,
                        const int* __restrict__ bsum, int nn) {
  int idx = blockIdx.x * blockDim.x + threadIdx.x;
  if (idx >= nn) return;
  int o = off[idx] + bsum[idx >> 10];
  off[idx] = o;
  cursor[idx] = o;
  dis[idx] = rsqrtf((float)indeg[idx] + 1.0f);  // +1 self-loop
}

// fill unified CSR straight from raw edge tensor; nontemporal 8 B scatter
// entry layout (little-endian): low word = src, high word = x[src]|f16(dis)<<16
__global__ void k_fill(const void* __restrict__ eir,
                       const int* __restrict__ xs, const float* __restrict__ dis,
                       int* __restrict__ cursor, long long* __restrict__ csr,
                       int nn, int ne, const int* __restrict__ flag64) {
  int e = blockIdx.x * blockDim.x + threadIdx.x;
  if (e >= ne) return;
  int is64 = *flag64;
  int s, d;
  if (is64) {
    s = (int)((const long long*)eir)[e];
    d = (int)((const long long*)eir)[ne + e];
  } else {
    s = ((const int*)eir)[e];
    d = ((const int*)eir)[ne + e];
  }
  s = s < 0 ? 0 : (s > nn - 1 ? nn - 1 : s);
  d = d < 0 ? 0 : (d > nn - 1 ? nn - 1 : d);
  unsigned short hb = __half_as_ushort(__float2half_rn(dis[s]));
  unsigned long long packed = (unsigned long long)((unsigned int)xs[s] |
                                                   ((unsigned int)hb << 16));
  unsigned long long entry = (unsigned long long)(unsigned int)s | (packed << 32);
  int pp = atomicAdd(&cursor[d], 1);
  __builtin_nontemporal_store((long long)entry, &csr[pp]);
}

// ---------------- G = emb @ W1 --------------------------------------------
__global__ void k_gemm_dumb(const float* __restrict__ A,
                            const float* __restrict__ W,
                            float* __restrict__ OUT, int rows) {
  int idx = blockIdx.x * blockDim.x + threadIdx.x;
  if (idx >= rows * D) return;
  int r = idx >> 7, c = idx & 127;
  const float* a = A + (size_t)r * D;
  float acc = 0.f;
  for (int k = 0; k < D; ++k) acc += a[k] * W[k * D + c];
  OUT[idx] = acc;
}

// ---- layer1: H1p[n] = dn * relu(dn*(dn*G[x[n]] + sum dis_s*G[x_s]) + b1) -
__global__ __launch_bounds__(256) void k_aggrelu(const int* __restrict__ x,
                                                 const float* __restrict__ G,
                                                 const float* __restrict__ b1,
                                                 const int* __restrict__ off,
                                                 const int* __restrict__ indeg,
                                                 const float* __restrict__ dis,
                                                 const int2* __restrict__ csr,
                                                 unsigned short* __restrict__ H1,
                                                 int nn) {
  int gid = blockIdx.x * blockDim.x + threadIdx.x;
  int n = gid >> 5;
  if (n >= nn) return;
  int lane = threadIdx.x & 31;
  float dn = dis[n];
  float4 g0 = ((const float4*)(G + (size_t)x[n] * D))[lane];
  float ax = dn * g0.x, ay = dn * g0.y, az = dn * g0.z, aw = dn * g0.w;
  int s0 = off[n], m = indeg[n];
  if (m >= 2) {
    unsigned int c0 = (unsigned int)csr[s0].y, c1 = (unsigned int)csr[s0 + 1].y;
    int j = 0;
    for (; j + 3 < m; j += 2) {
      unsigned int p0 = (unsigned int)csr[s0 + j + 2].y;
      unsigned int p1 = (unsigned int)csr[s0 + j + 3].y;
      float w0 = h2f((unsigned short)(c0 >> 16));
      float w1 = h2f((unsigned short)(c1 >> 16));
      float4 gA = ((const float4*)(G + (size_t)(c0 & 0xFFFF) * D))[lane];
      float4 gB = ((const float4*)(G + (size_t)(c1 & 0xFFFF) * D))[lane];
      ax += w0 * gA.x + w1 * gB.x;
      ay += w0 * gA.y + w1 * gB.y;
      az += w0 * gA.z + w1 * gB.z;
      aw += w0 * gA.w + w1 * gB.w;
      c0 = p0; c1 = p1;
    }
    {
      float w0 = h2f((unsigned short)(c0 >> 16));
      float w1 = h2f((unsigned short)(c1 >> 16));
      float4 gA = ((const float4*)(G + (size_t)(c0 & 0xFFFF) * D))[lane];
      float4 gB = ((const float4*)(G + (size_t)(c1 & 0xFFFF) * D))[lane];
      ax += w0 * gA.x + w1 * gB.x;
      ay += w0 * gA.y + w1 * gB.y;
      az += w0 * gA.z + w1 * gB.z;
      aw += w0 * gA.w + w1 * gB.w;
    }
    if (j + 2 < m) {
      unsigned int e0 = (unsigned int)csr[s0 + j + 2].y;
      float w0 = h2f((unsigned short)(e0 >> 16));
      float4 gA = ((const float4*)(G + (size_t)(e0 & 0xFFFF) * D))[lane];
      ax += w0 * gA.x; ay += w0 * gA.y; az += w0 * gA.z; aw += w0 * gA.w;
    }
  } else if (m == 1) {
    unsigned int e0 = (unsigned int)csr[s0].y;
    float w0 = h2f((unsigned short)(e0 >> 16));
    float4 gA = ((const float4*)(G + (size_t)(e0 & 0xFFFF) * D))[lane];
    ax += w0 * gA.x; ay += w0 * gA.y; az += w0 * gA.z; aw += w0 * gA.w;
  }
  float4 bb = ((const float4*)b1)[lane];
  ushort4 o;
  o.x = f2bf(dn * fmaxf(dn * ax + bb.x, 0.f));
  o.y = f2bf(dn * fmaxf(dn * ay + bb.y, 0.f));
  o.z = f2bf(dn * fmaxf(dn * az + bb.z, 0.f));
  o.w = f2bf(dn * fmaxf(dn * aw + bb.w, 0.f));
  ((ushort4*)(H1 + (size_t)n * D))[lane] = o;
}

// ---- fused layer2 + pool -------------------------------------------------
__global__ __launch_bounds__(256) void k_agg2pool(
    const unsigned short* __restrict__ H1, const int* __restrict__ off,
    const int* __restrict__ indeg, const float* __restrict__ dis,
    const int2* __restrict__ csr, const int* __restrict__ batch,
    float* __restrict__ P, int nn) {
  __shared__ float buf[8][D];
  __shared__ int gbuf[8];
  int t = threadIdx.x;
  int slot = t >> 5, lane = t & 31;
  int n = blockIdx.x * 8 + slot;
  float ax = 0.f, ay = 0.f, az = 0.f, aw = 0.f;
  if (n < nn) {
    float dn = dis[n];
    ushort4 u0 = ((const ushort4*)(H1 + (size_t)n * D))[lane];
    ax = bf2f(u0.x); ay = bf2f(u0.y); az = bf2f(u0.z); aw = bf2f(u0.w);
    int s0 = off[n], m = indeg[n];
    if (m >= 2) {
      int c0 = csr[s0].x, c1 = csr[s0 + 1].x;
      int j = 0;
      for (; j + 3 < m; j += 2) {
        int p0 = csr[s0 + j + 2].x;
        int p1 = csr[s0 + j + 3].x;
        ushort4 hA = ((const ushort4*)(H1 + (size_t)c0 * D))[lane];
        ushort4 hB = ((const ushort4*)(H1 + (size_t)c1 * D))[lane];
        ax += bf2f(hA.x) + bf2f(hB.x);
        ay += bf2f(hA.y) + bf2f(hB.y);
        az += bf2f(hA.z) + bf2f(hB.z);
        aw += bf2f(hA.w) + bf2f(hB.w);
        c0 = p0; c1 = p1;
      }
      {
        ushort4 hA = ((const ushort4*)(H1 + (size_t)c0 * D))[lane];
        ushort4 hB = ((const ushort4*)(H1 + (size_t)c1 * D))[lane];
        ax += bf2f(hA.x) + bf2f(hB.x);
        ay += bf2f(hA.y) + bf2f(hB.y);
        az += bf2f(hA.z) + bf2f(hB.z);
        aw += bf2f(hA.w) + bf2f(hB.w);
      }
      if (j + 2 < m) {
        int e0 = csr[s0 + j + 2].x;
        ushort4 hA = ((const ushort4*)(H1 + (size_t)e0 * D))[lane];
        ax += bf2f(hA.x); ay += bf2f(hA.y); az += bf2f(hA.z); aw += bf2f(hA.w);
      }
    } else if (m == 1) {
      int e0 = csr[s0].x;
      ushort4 hA = ((const ushort4*)(H1 + (size_t)e0 * D))[lane];
      ax += bf2f(hA.x); ay += bf2f(hA.y); az += bf2f(hA.z); aw += bf2f(hA.w);
    }
    ax *= dn; ay *= dn; az *= dn; aw *= dn;
  }
  ((float4*)&buf[slot][lane * 4])[0] = make_float4(ax, ay, az, aw);
  if (lane == 0) gbuf[slot] = (n < nn) ? batch[n] : -1;
  __syncthreads();
  if (t < D) {
    int c = t;
    float acc = 0.f;
    int run = -1;
    #pragma unroll
    for (int s2 = 0; s2 < 8; ++s2) {
      int g = gbuf[s2];
      if (g < 0) break;
      if (g != run) {
        if (run >= 0) atomicAdd(&P[(size_t)run * D + c], acc);
        run = g;
        acc = 0.f;
      }
      acc += buf[s2][c];
    }
    if (run >= 0) atomicAdd(&P[(size_t)run * D + c], acc);
  }
}

// ---- out: per-thread binary-search cnt, then GEMM row --------------------
__global__ void k_out_dumb(const float* __restrict__ P,
                           const int* __restrict__ batch,
                           const float* __restrict__ W2,
                           const float* __restrict__ b2,
                           float* __restrict__ Out, int nn, int ng) {
  int idx = blockIdx.x * blockDim.x + threadIdx.x;
  if (idx >= ng * D) return;
  int g = idx >> 7, c = idx & 127;
  int lo = 0, hi = nn;
  while (lo < hi) { int m = (lo + hi) >> 1; if (batch[m] < g) lo = m + 1; else hi = m; }
  int s = lo;
  hi = nn;
  while (lo < hi) { int m = (lo + hi) >> 1; if (batch[m] < g + 1) lo = m + 1; else hi = m; }
  int m = lo - s;
  float inv = (m > 0) ? (1.0f / (float)m) : 0.0f;
  const float* pr = P + (size_t)g * D;
  float acc = 0.f;
  for (int k = 0; k < D; ++k) acc += pr[k] * W2[k * D + c];
  acc *= inv;
  if (m > 0) acc += b2[c];
  Out[idx] = acc;
}

extern "C" void kernel_launch(void* const* d_in, const int* in_sizes, int n_in,
                              void* d_out, int out_size, void* d_ws, size_t ws_size,
                              hipStream_t stream) {
  const void* xr = d_in[0];
  const void* eir = d_in[1];
  const void* batchr = d_in[2];
  const void* emb = d_in[3];
  const void* W1 = d_in[4];
  const void* b1 = d_in[5];
  const void* W2 = d_in[6];
  const void* b2 = d_in[7];
  float* out = (float*)d_out;

  const int nn = in_sizes[0];
  const int ne = in_sizes[1] / 2;
  const int vocab = in_sizes[3] / D;
  const int ng = out_size / D;
  const int nb = (nn + 1023) / 1024;

  char* p = (char*)d_ws;
  auto alloc = [&](size_t bytes) -> char* {
    char* r = p;
    p += (bytes + 511) & ~(size_t)511;
    return r;
  };
  int* flag = (int*)alloc(512);
  int* xs = (int*)alloc((size_t)nn * 4);
  int* batchs = (int*)alloc((size_t)nn * 4);
  int* indeg = (int*)alloc((size_t)nn * 4);
  int* off = (int*)alloc((size_t)nn * 4);
  int* cursor = (int*)alloc((size_t)nn * 4);
  float* dis = (float*)alloc((size_t)nn * 4);
  int* bsum = (int*)alloc((size_t)nb * 4);
  long long* csr = (long long*)alloc((size_t)ne * 8);
  float* embf = (float*)alloc((size_t)vocab * D * 4);
  float* W1f = (float*)alloc((size_t)D * D * 4);
  float* b1f = (float*)alloc((size_t)D * 4);
  float* W2f = (float*)alloc((size_t)D * D * 4);
  float* b2f = (float*)alloc((size_t)D * 4);
  float* G = (float*)alloc((size_t)vocab * D * 4);
  unsigned short* H1 = (unsigned short*)alloc((size_t)nn * D * 2);
  float* P = (float*)alloc((size_t)ng * D * 4);

  (void)hipMemsetAsync(flag, 0, 512, stream);
  (void)hipMemsetAsync(indeg, 0, (size_t)nn * 4, stream);
  (void)hipMemsetAsync(P, 0, (size_t)ng * D * 4, stream);

  k_detect_f5<<<5, 256, 0, stream>>>(
      (const unsigned short*)emb, vocab * D,
      (const unsigned short*)W1, D * D,
      (const unsigned short*)b1, D,
      (const unsigned short*)W2, D * D,
      (const unsigned short*)b2, D, flag);
  k_detect_i<<<1, 64, 0, stream>>>((const unsigned int*)eir, flag + 5);

  k_conv<<<(vocab * D + 255) / 256, 256, 0, stream>>>(emb, embf, vocab * D, flag + 0);
  k_conv_params<<<(2 * D * D + 2 * D + 255) / 256, 256, 0, stream>>>(
      W1, b1, W2, b2, W1f, b1f, W2f, b2f, flag);

  {
    long long tot = 2LL * nn + ne;
    k_convi_all<<<(int)((tot + 255) / 256), 256, 0, stream>>>(
        xr, eir, batchr, xs, batchs, indeg, nn, ne, vocab, ng, flag + 5);
  }

  k_scan1<<<nb, 1024, 0, stream>>>(indeg, off, bsum, nn);
  k_scan2<<<1, 64, 0, stream>>>(bsum, nb);
  k_scan3<<<(nn + 255) / 256, 256, 0, stream>>>(off, cursor, dis, indeg, bsum, nn);
  k_fill<<<(ne + 255) / 256, 256, 0, stream>>>(eir, xs, dis, cursor, csr, nn, ne,
                                               flag + 5);

  k_gemm_dumb<<<(vocab * D + 255) / 256, 256, 0, stream>>>(embf, W1f, G, vocab);

  {
    long long thr = (long long)nn * 32;
    k_aggrelu<<<(int)((thr + 255) / 256), 256, 0, stream>>>(xs, G, b1f, off, indeg,
                                                            dis, (const int2*)csr,
                                                            H1, nn);
  }
  k_agg2pool<<<(nn + 7) / 8, 256, 0, stream>>>(H1, off, indeg, dis,
                                               (const int2*)csr, batchs, P, nn);
  k_out_dumb<<<(ng * D + 255) / 256, 256, 0, stream>>>(P, batchs, W2f, b2f, out,
                                                       nn, ng);
}